// Round 8
// baseline (210.571 us; speedup 1.0000x reference)
//
#include <hip/hip_runtime.h>
#include <hip/hip_bf16.h>

#define N_ROWS 4096
#define DIM 512
#define TWO_N 8192
#define NTILE 64                 // 8192 / 128
#define NTRI  (NTILE * (NTILE + 1) / 2)   // 2080 upper-tri 128x128 blocks

typedef __bf16 bf16x8 __attribute__((ext_vector_type(8)));
typedef float  f32x4  __attribute__((ext_vector_type(4)));

// ---------------------------------------------------------------------------
// round-to-nearest-even float -> bf16 bits
__device__ inline unsigned short f2bf(float f) {
    unsigned int u = __float_as_uint(f);
    u += 0x7fffu + ((u >> 16) & 1u);
    return (unsigned short)(u >> 16);
}

// async global -> LDS, 16 bytes per lane (wave-uniform LDS base + lane*16)
__device__ inline void g2l16(const void* g, void* l) {
    __builtin_amdgcn_global_load_lds(
        (const __attribute__((address_space(1))) void*)g,
        (__attribute__((address_space(3))) void*)l,
        16, 0, 0);
}

// ---------------------------------------------------------------------------
// Kernel 1: normalize rows of emb_i / emb_j (proven, unchanged).
__global__ void normalize_kernel(const float* __restrict__ ei,
                                 const float* __restrict__ ej,
                                 unsigned short* __restrict__ zb,
                                 float* __restrict__ pos,
                                 float* __restrict__ denom,
                                 float* __restrict__ out) {
    int r = blockIdx.x;          // 0..4095
    int t = threadIdx.x;         // 0..255
    const float2 vi = ((const float2*)(ei + (size_t)r * DIM))[t];
    const float2 vj = ((const float2*)(ej + (size_t)r * DIM))[t];
    float si  = vi.x * vi.x + vi.y * vi.y;
    float sj  = vj.x * vj.x + vj.y * vj.y;
    float sij = vi.x * vj.x + vi.y * vj.y;

    for (int o = 32; o; o >>= 1) {
        si  += __shfl_down(si, o);
        sj  += __shfl_down(sj, o);
        sij += __shfl_down(sij, o);
    }
    __shared__ float red[3][4];
    int wave = t >> 6, lane = t & 63;
    if (lane == 0) { red[0][wave] = si; red[1][wave] = sj; red[2][wave] = sij; }
    __syncthreads();
    si  = red[0][0] + red[0][1] + red[0][2] + red[0][3];
    sj  = red[1][0] + red[1][1] + red[1][2] + red[1][3];
    sij = red[2][0] + red[2][1] + red[2][2] + red[2][3];

    float rni = 1.0f / fmaxf(sqrtf(si), 1e-12f);
    float rnj = 1.0f / fmaxf(sqrtf(sj), 1e-12f);
    if (t == 0) {
        pos[r] = sij * rni * rnj;
        denom[r] = 0.0f;
        denom[r + N_ROWS] = 0.0f;
        if (r == 0) out[0] = 0.0f;
    }
    ushort2 zi2 = make_ushort2(f2bf(vi.x * rni), f2bf(vi.y * rni));
    ushort2 zj2 = make_ushort2(f2bf(vj.x * rnj), f2bf(vj.y * rnj));
    ((ushort2*)(zb + (size_t)r * DIM))[t] = zi2;
    ((ushort2*)(zb + (size_t)(r + N_ROWS) * DIM))[t] = zj2;
}

// ---------------------------------------------------------------------------
// Kernel 2 (v8): v4's proven 128x128 BK=64 structure (54 us, 646 TF) plus:
//  (1) XCD-chunked block swizzle: tix = (w&7)*260 + (w>>3)  [2080 = 8*260,
//      bijective]. Blocks sharing A row-panels co-locate on one XCD ->
//      A-panel re-reads become L2 hits instead of L3 traffic.
//  (2) diag blocks (B==A) skip B staging and read B-frags from As.
//  (3) __launch_bounds__(256,5): 5 blocks/CU (LDS 32KB, VGPR 64 << 102).
//
// LDS layout/swizzle PMC-proven 0 bank conflicts: row = 64 ush = 8 x 16B
// granules; phys slot = logical ^ (row&7); staged via pre-swizzled global
// source (linear LDS dest); frag read slot ((h*4+quad)^(m&7)).
__global__ __launch_bounds__(256, 5) void gemm_exp_kernel(
        const unsigned short* __restrict__ zb,
        float* __restrict__ denom) {
    // ---- XCD-chunked swizzle, then linear index -> (by, bx), by <= bx ----
    const int w = blockIdx.x;
    const int t = (w & 7) * (NTRI / 8) + (w >> 3);
    int by = (int)(0.5f * (2.0f * NTILE + 1.0f -
              sqrtf((2.0f * NTILE + 1.0f) * (2.0f * NTILE + 1.0f) - 8.0f * t)));
    while ((by + 1) * NTILE - ((by + 1) * by) / 2 <= t) ++by;
    while (by * NTILE - (by * (by - 1)) / 2 > t) --by;
    const int bx = by + (t - (by * NTILE - (by * (by - 1)) / 2));

    const int rb = by * 128, cb = bx * 128;
    const bool diag = (rb == cb);

    const int tid  = threadIdx.x;
    const int wave = tid >> 6;
    const int lane = tid & 63;
    const int quad = lane >> 4;          // 0..3
    const int m    = lane & 15;          // 0..15
    const int wm   = (wave >> 1) * 64;   // wave row offset in tile
    const int wn   = (wave & 1) * 64;    // wave col offset in tile

    __shared__ __align__(16) unsigned short As[128 * 64];
    __shared__ __align__(16) unsigned short Bs[128 * 64];

    f32x4 acc[4][4];
    #pragma unroll
    for (int i = 0; i < 4; ++i)
        #pragma unroll
        for (int j = 0; j < 4; ++j)
            #pragma unroll
            for (int r = 0; r < 4; ++r) acc[i][j][r] = 0.0f;

    // staging: chunk = 1KB = 8 rows x 8 granules; wave w stages chunks
    // 4w..4w+3 of A (and B unless diag).
    const int srow8 = lane >> 3;                     // row within chunk
    const int sk    = (((lane & 7) ^ srow8) * 8);    // pre-swizzled granule

    const unsigned short* Bbase = diag ? As : Bs;    // diag: B-frags from As

    for (int it = 0; it < DIM / 64; ++it) {
        if (it) __syncthreads();         // readers of previous tile done
        const int k0 = it * 64;
        #pragma unroll
        for (int cc = 0; cc < 4; ++cc) {
            int c   = 4 * wave + cc;
            int row = c * 8 + srow8;
            g2l16(zb + (size_t)(rb + row) * DIM + k0 + sk, As + c * 512);
            if (!diag)
                g2l16(zb + (size_t)(cb + row) * DIM + k0 + sk, Bs + c * 512);
        }
        __syncthreads();                 // implicit vmcnt drain: tile visible

        #pragma unroll
        for (int h = 0; h < 2; ++h) {    // two K=32 halves of the BK=64 tile
            bf16x8 af[4], bfr[4];
            const int sl = ((((h << 2) | quad) ^ (m & 7)) * 8);
            #pragma unroll
            for (int i = 0; i < 4; ++i)
                af[i] = *(const bf16x8*)(As + (wm + i * 16 + m) * 64 + sl);
            #pragma unroll
            for (int j = 0; j < 4; ++j)
                bfr[j] = *(const bf16x8*)(Bbase + (wn + j * 16 + m) * 64 + sl);

            #pragma unroll
            for (int i = 0; i < 4; ++i)
                #pragma unroll
                for (int j = 0; j < 4; ++j)
                    acc[i][j] = __builtin_amdgcn_mfma_f32_16x16x32_bf16(
                        af[i], bfr[j], acc[i][j], 0, 0, 0);
        }
    }

    // all waves done with final ds_reads before reusing As as scratch
    __syncthreads();

    // ---- epilogue: exp(2*sim), mask diag, row sums (+ col sums off-diag) ----
    float* rs = (float*)As;            // reuse LDS: rowsum[128] | colsum[128]
    float* cs = rs + 128;
    if (tid < 128) { rs[tid] = 0.0f; cs[tid] = 0.0f; }
    __syncthreads();

    float colsum[4] = {0.0f, 0.0f, 0.0f, 0.0f};
    #pragma unroll
    for (int i = 0; i < 4; ++i) {
        #pragma unroll
        for (int r = 0; r < 4; ++r) {
            int lrow = wm + i * 16 + quad * 4 + r;    // local row 0..127
            int grow = rb + lrow;
            float s = 0.0f;
            #pragma unroll
            for (int j = 0; j < 4; ++j) {
                int gcol = cb + wn + j * 16 + m;
                float v  = __expf(2.0f * acc[i][j][r]);
                v = (grow == gcol) ? 0.0f : v;
                s += v;
                colsum[j] += v;
            }
            // sum across the 16 lanes of this quad-row group (bits 0..3)
            s += __shfl_xor(s, 1);
            s += __shfl_xor(s, 2);
            s += __shfl_xor(s, 4);
            s += __shfl_xor(s, 8);
            if (m == 0) atomicAdd(&rs[lrow], s);
        }
    }
    if (!diag) {
        #pragma unroll
        for (int j = 0; j < 4; ++j) {
            float s = colsum[j];       // this wave's 64 rows, col wn+j*16+m
            s += __shfl_xor(s, 16);    // combine across quads (rows)
            s += __shfl_xor(s, 32);
            if (quad == 0) atomicAdd(&cs[wn + j * 16 + m], s);
        }
    }
    __syncthreads();
    if (tid < 128) {
        atomicAdd(&denom[rb + tid], rs[tid]);
        if (!diag) atomicAdd(&denom[cb + tid], cs[tid]);
    }
}

// ---------------------------------------------------------------------------
// Kernel 3: loss (proven, unchanged).
__global__ void loss_kernel(const float* __restrict__ pos,
                            const float* __restrict__ denom,
                            float* __restrict__ out) {
    int r = blockIdx.x * 256 + threadIdx.x;   // 0..8191
    float s = __logf(denom[r]) - 2.0f * pos[r & (N_ROWS - 1)];
    for (int o = 32; o; o >>= 1) s += __shfl_down(s, o);
    __shared__ float red[4];
    int t = threadIdx.x;
    if ((t & 63) == 0) red[t >> 6] = s;
    __syncthreads();
    if (t == 0)
        atomicAdd(out, (red[0] + red[1] + red[2] + red[3]) / (float)TWO_N);
}

// ---------------------------------------------------------------------------
extern "C" void kernel_launch(void* const* d_in, const int* in_sizes, int n_in,
                              void* d_out, int out_size, void* d_ws, size_t ws_size,
                              hipStream_t stream) {
    const float* ei = (const float*)d_in[0];
    const float* ej = (const float*)d_in[1];

    // ws layout: zb (bf16, 2N*D = 8 MB) | pos (N f32) | denom (2N f32)
    unsigned short* zb  = (unsigned short*)d_ws;
    float* pos   = (float*)((char*)d_ws + (size_t)TWO_N * DIM * sizeof(unsigned short));
    float* denom = pos + N_ROWS;
    float* out   = (float*)d_out;

    normalize_kernel<<<N_ROWS, 256, 0, stream>>>(ei, ej, zb, pos, denom, out);
    gemm_exp_kernel<<<NTRI, 256, 0, stream>>>(zb, denom);
    loss_kernel<<<TWO_N / 256, 256, 0, stream>>>(pos, denom, out);
}

// Round 9
// 119.184 us; speedup vs baseline: 1.7668x; 1.7668x over previous
//
#include <hip/hip_runtime.h>
#include <hip/hip_bf16.h>

#define N_ROWS 4096
#define DIM 512
#define TWO_N 8192
#define NTILE 64                 // 8192 / 128
#define NTRI  (NTILE * (NTILE + 1) / 2)   // 2080 upper-tri 128x128 blocks

typedef __bf16 bf16x8 __attribute__((ext_vector_type(8)));
typedef float  f32x4  __attribute__((ext_vector_type(4)));

// ---------------------------------------------------------------------------
// round-to-nearest-even float -> bf16 bits
__device__ inline unsigned short f2bf(float f) {
    unsigned int u = __float_as_uint(f);
    u += 0x7fffu + ((u >> 16) & 1u);
    return (unsigned short)(u >> 16);
}

// async global -> LDS, 16 bytes per lane (wave-uniform LDS base + lane*16)
__device__ inline void g2l16(const void* g, void* l) {
    __builtin_amdgcn_global_load_lds(
        (const __attribute__((address_space(1))) void*)g,
        (__attribute__((address_space(3))) void*)l,
        16, 0, 0);
}

// ---------------------------------------------------------------------------
// Kernel 1: normalize rows of emb_i / emb_j (proven, unchanged).
__global__ void normalize_kernel(const float* __restrict__ ei,
                                 const float* __restrict__ ej,
                                 unsigned short* __restrict__ zb,
                                 float* __restrict__ pos,
                                 float* __restrict__ denom,
                                 float* __restrict__ out) {
    int r = blockIdx.x;          // 0..4095
    int t = threadIdx.x;         // 0..255
    const float2 vi = ((const float2*)(ei + (size_t)r * DIM))[t];
    const float2 vj = ((const float2*)(ej + (size_t)r * DIM))[t];
    float si  = vi.x * vi.x + vi.y * vi.y;
    float sj  = vj.x * vj.x + vj.y * vj.y;
    float sij = vi.x * vj.x + vi.y * vj.y;

    for (int o = 32; o; o >>= 1) {
        si  += __shfl_down(si, o);
        sj  += __shfl_down(sj, o);
        sij += __shfl_down(sij, o);
    }
    __shared__ float red[3][4];
    int wave = t >> 6, lane = t & 63;
    if (lane == 0) { red[0][wave] = si; red[1][wave] = sj; red[2][wave] = sij; }
    __syncthreads();
    si  = red[0][0] + red[0][1] + red[0][2] + red[0][3];
    sj  = red[1][0] + red[1][1] + red[1][2] + red[1][3];
    sij = red[2][0] + red[2][1] + red[2][2] + red[2][3];

    float rni = 1.0f / fmaxf(sqrtf(si), 1e-12f);
    float rnj = 1.0f / fmaxf(sqrtf(sj), 1e-12f);
    if (t == 0) {
        pos[r] = sij * rni * rnj;
        denom[r] = 0.0f;
        denom[r + N_ROWS] = 0.0f;
        if (r == 0) out[0] = 0.0f;
    }
    ushort2 zi2 = make_ushort2(f2bf(vi.x * rni), f2bf(vi.y * rni));
    ushort2 zj2 = make_ushort2(f2bf(vj.x * rnj), f2bf(vj.y * rnj));
    ((ushort2*)(zb + (size_t)r * DIM))[t] = zi2;
    ((ushort2*)(zb + (size_t)(r + N_ROWS) * DIM))[t] = zj2;
}

// ---------------------------------------------------------------------------
// Kernel 2 (v9): EXACT v4 structure (54.0 us proven: launch_bounds(256,4),
// VGPR 64, no spills) + ONE change: bijective XCD-chunked block swizzle
// tix = (w&7)*260 + (w>>3)  [2080 = 8*260]. Consecutive tri-tiles share
// A row-panels; chunking co-locates them on one XCD so panel re-reads hit
// that XCD's private L2 instead of L3/HBM.
//
// LDS layout/swizzle PMC-proven 0 bank conflicts: row = 64 ush = 8 x 16B
// granules; phys slot = logical ^ (row&7); staged via pre-swizzled global
// source (linear LDS dest); frag read slot ((h*4+quad)^(m&7)).
__global__ __launch_bounds__(256, 4) void gemm_exp_kernel(
        const unsigned short* __restrict__ zb,
        float* __restrict__ denom) {
    // ---- XCD-chunked swizzle, then linear index -> (by, bx), by <= bx ----
    const int w = blockIdx.x;
    const int t = (w & 7) * (NTRI / 8) + (w >> 3);
    int by = (int)(0.5f * (2.0f * NTILE + 1.0f -
              sqrtf((2.0f * NTILE + 1.0f) * (2.0f * NTILE + 1.0f) - 8.0f * t)));
    while ((by + 1) * NTILE - ((by + 1) * by) / 2 <= t) ++by;
    while (by * NTILE - (by * (by - 1)) / 2 > t) --by;
    const int bx = by + (t - (by * NTILE - (by * (by - 1)) / 2));

    const int rb = by * 128, cb = bx * 128;
    const bool diag = (rb == cb);

    const int tid  = threadIdx.x;
    const int wave = tid >> 6;
    const int lane = tid & 63;
    const int quad = lane >> 4;          // 0..3
    const int m    = lane & 15;          // 0..15
    const int wm   = (wave >> 1) * 64;   // wave row offset in tile
    const int wn   = (wave & 1) * 64;    // wave col offset in tile

    __shared__ __align__(16) unsigned short As[128 * 64];
    __shared__ __align__(16) unsigned short Bs[128 * 64];

    f32x4 acc[4][4];
    #pragma unroll
    for (int i = 0; i < 4; ++i)
        #pragma unroll
        for (int j = 0; j < 4; ++j)
            #pragma unroll
            for (int r = 0; r < 4; ++r) acc[i][j][r] = 0.0f;

    // staging: chunk = 1KB = 8 rows x 8 granules; wave w stages chunks
    // 4w..4w+3 of A and B (8 g2l16 per wave per K-step).
    const int srow8 = lane >> 3;                     // row within chunk
    const int sk    = (((lane & 7) ^ srow8) * 8);    // pre-swizzled granule

    for (int it = 0; it < DIM / 64; ++it) {
        if (it) __syncthreads();         // readers of previous tile done
        const int k0 = it * 64;
        #pragma unroll
        for (int cc = 0; cc < 4; ++cc) {
            int c   = 4 * wave + cc;
            int row = c * 8 + srow8;
            g2l16(zb + (size_t)(rb + row) * DIM + k0 + sk, As + c * 512);
            g2l16(zb + (size_t)(cb + row) * DIM + k0 + sk, Bs + c * 512);
        }
        __syncthreads();                 // implicit vmcnt drain: tile visible

        #pragma unroll
        for (int h = 0; h < 2; ++h) {    // two K=32 halves of the BK=64 tile
            bf16x8 af[4], bfr[4];
            const int sl = ((((h << 2) | quad) ^ (m & 7)) * 8);
            #pragma unroll
            for (int i = 0; i < 4; ++i)
                af[i] = *(const bf16x8*)(As + (wm + i * 16 + m) * 64 + sl);
            #pragma unroll
            for (int j = 0; j < 4; ++j)
                bfr[j] = *(const bf16x8*)(Bs + (wn + j * 16 + m) * 64 + sl);

            #pragma unroll
            for (int i = 0; i < 4; ++i)
                #pragma unroll
                for (int j = 0; j < 4; ++j)
                    acc[i][j] = __builtin_amdgcn_mfma_f32_16x16x32_bf16(
                        af[i], bfr[j], acc[i][j], 0, 0, 0);
        }
    }

    // all waves done with final ds_reads before reusing As as scratch
    __syncthreads();

    // ---- epilogue: exp(2*sim), mask diag, row sums (+ col sums off-diag) ----
    float* rs = (float*)As;            // reuse LDS: rowsum[128] | colsum[128]
    float* cs = rs + 128;
    if (tid < 128) { rs[tid] = 0.0f; cs[tid] = 0.0f; }
    __syncthreads();

    float colsum[4] = {0.0f, 0.0f, 0.0f, 0.0f};
    #pragma unroll
    for (int i = 0; i < 4; ++i) {
        #pragma unroll
        for (int r = 0; r < 4; ++r) {
            int lrow = wm + i * 16 + quad * 4 + r;    // local row 0..127
            int grow = rb + lrow;
            float s = 0.0f;
            #pragma unroll
            for (int j = 0; j < 4; ++j) {
                int gcol = cb + wn + j * 16 + m;
                float v  = __expf(2.0f * acc[i][j][r]);
                v = (grow == gcol) ? 0.0f : v;
                s += v;
                colsum[j] += v;
            }
            // sum across the 16 lanes of this quad-row group (bits 0..3)
            s += __shfl_xor(s, 1);
            s += __shfl_xor(s, 2);
            s += __shfl_xor(s, 4);
            s += __shfl_xor(s, 8);
            if (m == 0) atomicAdd(&rs[lrow], s);
        }
    }
    if (!diag) {
        #pragma unroll
        for (int j = 0; j < 4; ++j) {
            float s = colsum[j];       // this wave's 64 rows, col wn+j*16+m
            s += __shfl_xor(s, 16);    // combine across quads (rows)
            s += __shfl_xor(s, 32);
            if (quad == 0) atomicAdd(&cs[wn + j * 16 + m], s);
        }
    }
    __syncthreads();
    if (tid < 128) {
        atomicAdd(&denom[rb + tid], rs[tid]);
        if (!diag) atomicAdd(&denom[cb + tid], cs[tid]);
    }
}

// ---------------------------------------------------------------------------
// Kernel 3: loss (proven, unchanged).
__global__ void loss_kernel(const float* __restrict__ pos,
                            const float* __restrict__ denom,
                            float* __restrict__ out) {
    int r = blockIdx.x * 256 + threadIdx.x;   // 0..8191
    float s = __logf(denom[r]) - 2.0f * pos[r & (N_ROWS - 1)];
    for (int o = 32; o; o >>= 1) s += __shfl_down(s, o);
    __shared__ float red[4];
    int t = threadIdx.x;
    if ((t & 63) == 0) red[t >> 6] = s;
    __syncthreads();
    if (t == 0)
        atomicAdd(out, (red[0] + red[1] + red[2] + red[3]) / (float)TWO_N);
}

// ---------------------------------------------------------------------------
extern "C" void kernel_launch(void* const* d_in, const int* in_sizes, int n_in,
                              void* d_out, int out_size, void* d_ws, size_t ws_size,
                              hipStream_t stream) {
    const float* ei = (const float*)d_in[0];
    const float* ej = (const float*)d_in[1];

    // ws layout: zb (bf16, 2N*D = 8 MB) | pos (N f32) | denom (2N f32)
    unsigned short* zb  = (unsigned short*)d_ws;
    float* pos   = (float*)((char*)d_ws + (size_t)TWO_N * DIM * sizeof(unsigned short));
    float* denom = pos + N_ROWS;
    float* out   = (float*)d_out;

    normalize_kernel<<<N_ROWS, 256, 0, stream>>>(ei, ej, zb, pos, denom, out);
    gemm_exp_kernel<<<NTRI, 256, 0, stream>>>(zb, denom);
    loss_kernel<<<TWO_N / 256, 256, 0, stream>>>(pos, denom, out);
}

// Round 10
// 107.233 us; speedup vs baseline: 1.9637x; 1.1114x over previous
//
#include <hip/hip_runtime.h>
#include <hip/hip_bf16.h>

#define N_ROWS 4096
#define DIM 512                  // elements AND bytes per fp8 row
#define TWO_N 8192
#define NTILE 64                 // 8192 / 128
#define NTRI  (NTILE * (NTILE + 1) / 2)   // 2080 upper-tri 128x128 blocks

typedef float f32x4 __attribute__((ext_vector_type(4)));

// ---------------------------------------------------------------------------
// async global -> LDS, 16 bytes per lane (wave-uniform LDS base + lane*16)
__device__ inline void g2l16(const void* g, void* l) {
    __builtin_amdgcn_global_load_lds(
        (const __attribute__((address_space(1))) void*)g,
        (__attribute__((address_space(3))) void*)l,
        16, 0, 0);
}

// ---------------------------------------------------------------------------
// Kernel 1: normalize rows of emb_i / emb_j; emit fp8-e4m3 z rows (1 B/elem)
// via v_cvt_pk_fp8_f32; pos[] stays full f32 (exact positives). Also zeros
// denom and out.
__global__ void normalize_kernel(const float* __restrict__ ei,
                                 const float* __restrict__ ej,
                                 unsigned char* __restrict__ zq,
                                 float* __restrict__ pos,
                                 float* __restrict__ denom,
                                 float* __restrict__ out) {
    int r = blockIdx.x;          // 0..4095
    int t = threadIdx.x;         // 0..255, 2 dims each
    const float2 vi = ((const float2*)(ei + (size_t)r * DIM))[t];
    const float2 vj = ((const float2*)(ej + (size_t)r * DIM))[t];
    float si  = vi.x * vi.x + vi.y * vi.y;
    float sj  = vj.x * vj.x + vj.y * vj.y;
    float sij = vi.x * vj.x + vi.y * vj.y;

    for (int o = 32; o; o >>= 1) {
        si  += __shfl_down(si, o);
        sj  += __shfl_down(sj, o);
        sij += __shfl_down(sij, o);
    }
    __shared__ float red[3][4];
    int wave = t >> 6, lane = t & 63;
    if (lane == 0) { red[0][wave] = si; red[1][wave] = sj; red[2][wave] = sij; }
    __syncthreads();
    si  = red[0][0] + red[0][1] + red[0][2] + red[0][3];
    sj  = red[1][0] + red[1][1] + red[1][2] + red[1][3];
    sij = red[2][0] + red[2][1] + red[2][2] + red[2][3];

    float rni = 1.0f / fmaxf(sqrtf(si), 1e-12f);
    float rnj = 1.0f / fmaxf(sqrtf(sj), 1e-12f);
    if (t == 0) {
        pos[r] = sij * rni * rnj;
        denom[r] = 0.0f;
        denom[r + N_ROWS] = 0.0f;
        if (r == 0) out[0] = 0.0f;
    }
    // pack 2 f32 -> 2 fp8 e4m3 (OCP, RNE) in one HW instruction
    int pi8 = __builtin_amdgcn_cvt_pk_fp8_f32(vi.x * rni, vi.y * rni, 0, false);
    int pj8 = __builtin_amdgcn_cvt_pk_fp8_f32(vj.x * rnj, vj.y * rnj, 0, false);
    ((unsigned short*)(zq + (size_t)r * DIM))[t] = (unsigned short)pi8;
    ((unsigned short*)(zq + (size_t)(r + N_ROWS) * DIM))[t] = (unsigned short)pj8;
}

// ---------------------------------------------------------------------------
// Kernel 2 (v10): v9's proven structure (128x128 tri-tile, XCD-chunked
// swizzle, launch_bounds(256,4), 0-conflict granule swizzle) ported to
// fp8-e4m3 staging + mfma_f32_16x16x32_fp8_fp8 (bf16-rate MFMA, half bytes):
//   - staged bytes/block: 256 KB -> 128 KB (533 -> 267 MB total)
//   - K-tile = 128 B -> row = 128 B = 8 x 16B granules: IDENTICAL swizzle
//     geometry to the PMC-proven bf16 BK=64 layout.
//   - K-steps 8 -> 4: per-tile barrier/drain count halves (the proven R3
//     lever applied again).
//   - frag reads: ds_read_b64 at phys = ((s8>>1) ^ (m&7))*16 + (s8&1)*8,
//     s8 = kk*4+quad -> lanes m and m+8 share a bank set (2-way = free).
__global__ __launch_bounds__(256, 4) void gemm_exp_kernel(
        const unsigned char* __restrict__ zq,
        float* __restrict__ denom) {
    // ---- XCD-chunked swizzle (proven R9), then linear -> (by, bx) ----
    const int w = blockIdx.x;
    const int t = (w & 7) * (NTRI / 8) + (w >> 3);
    int by = (int)(0.5f * (2.0f * NTILE + 1.0f -
              sqrtf((2.0f * NTILE + 1.0f) * (2.0f * NTILE + 1.0f) - 8.0f * t)));
    while ((by + 1) * NTILE - ((by + 1) * by) / 2 <= t) ++by;
    while (by * NTILE - (by * (by - 1)) / 2 > t) --by;
    const int bx = by + (t - (by * NTILE - (by * (by - 1)) / 2));

    const int rb = by * 128, cb = bx * 128;
    const bool diag = (rb == cb);

    const int tid  = threadIdx.x;
    const int wave = tid >> 6;
    const int lane = tid & 63;
    const int quad = lane >> 4;          // 0..3
    const int m    = lane & 15;          // 0..15
    const int wm   = (wave >> 1) * 64;   // wave row offset in tile
    const int wn   = (wave & 1) * 64;    // wave col offset in tile

    __shared__ __align__(16) unsigned char As[128 * 128];   // 16 KB
    __shared__ __align__(16) unsigned char Bs[128 * 128];   // 16 KB

    f32x4 acc[4][4];
    #pragma unroll
    for (int i = 0; i < 4; ++i)
        #pragma unroll
        for (int j = 0; j < 4; ++j)
            #pragma unroll
            for (int r = 0; r < 4; ++r) acc[i][j][r] = 0.0f;

    // staging: chunk = 1KB = 8 rows x 8 granules(16B); wave w stages chunks
    // 4w..4w+3 of A and B. lane l -> row l>>3, phys granule l&7, holding
    // global granule (l&7)^(l>>3)  => phys slot s at row r = logical s^(r&7).
    const int srow8 = lane >> 3;
    const int sk    = (((lane & 7) ^ srow8) * 16);   // pre-swizzled src bytes

    for (int it = 0; it < 4; ++it) {     // 4 K-tiles of 128 B
        if (it) __syncthreads();         // readers of previous tile done
        const int k0 = it * 128;         // byte offset in row
        #pragma unroll
        for (int cc = 0; cc < 4; ++cc) {
            int c   = 4 * wave + cc;
            int row = c * 8 + srow8;
            g2l16(zq + (size_t)(rb + row) * DIM + k0 + sk, As + c * 1024);
            g2l16(zq + (size_t)(cb + row) * DIM + k0 + sk, Bs + c * 1024);
        }
        __syncthreads();                 // implicit vmcnt drain: tile visible

        #pragma unroll
        for (int kk = 0; kk < 4; ++kk) { // four K=32 sub-steps
            const int s8 = kk * 4 + quad;                    // logical 8B slot
            const int sl = (((s8 >> 1) ^ (m & 7)) * 16) + (s8 & 1) * 8;
            long long af[4], bfr[4];
            #pragma unroll
            for (int i = 0; i < 4; ++i)
                af[i] = *(const long long*)(As + (wm + i * 16 + m) * 128 + sl);
            #pragma unroll
            for (int j = 0; j < 4; ++j)
                bfr[j] = *(const long long*)(Bs + (wn + j * 16 + m) * 128 + sl);

            #pragma unroll
            for (int i = 0; i < 4; ++i)
                #pragma unroll
                for (int j = 0; j < 4; ++j)
                    acc[i][j] = __builtin_amdgcn_mfma_f32_16x16x32_fp8_fp8(
                        af[i], bfr[j], acc[i][j], 0, 0, 0);
        }
    }

    // all waves done with final ds_reads before reusing As as scratch
    __syncthreads();

    // ---- epilogue: exp(2*sim), mask diag, row sums (+ col sums off-diag) ----
    float* rs = (float*)As;            // rowsum[128] | colsum[128]
    float* cs = rs + 128;
    if (tid < 128) { rs[tid] = 0.0f; cs[tid] = 0.0f; }
    __syncthreads();

    float colsum[4] = {0.0f, 0.0f, 0.0f, 0.0f};
    #pragma unroll
    for (int i = 0; i < 4; ++i) {
        #pragma unroll
        for (int r = 0; r < 4; ++r) {
            int lrow = wm + i * 16 + quad * 4 + r;    // local row 0..127
            int grow = rb + lrow;
            float s = 0.0f;
            #pragma unroll
            for (int j = 0; j < 4; ++j) {
                int gcol = cb + wn + j * 16 + m;
                float v  = __expf(2.0f * acc[i][j][r]);
                v = (grow == gcol) ? 0.0f : v;
                s += v;
                colsum[j] += v;
            }
            s += __shfl_xor(s, 1);
            s += __shfl_xor(s, 2);
            s += __shfl_xor(s, 4);
            s += __shfl_xor(s, 8);
            if (m == 0) atomicAdd(&rs[lrow], s);
        }
    }
    if (!diag) {
        #pragma unroll
        for (int j = 0; j < 4; ++j) {
            float s = colsum[j];       // this wave's 64 rows, col wn+j*16+m
            s += __shfl_xor(s, 16);
            s += __shfl_xor(s, 32);
            if (quad == 0) atomicAdd(&cs[wn + j * 16 + m], s);
        }
    }
    __syncthreads();
    if (tid < 128) {
        atomicAdd(&denom[rb + tid], rs[tid]);
        if (!diag) atomicAdd(&denom[cb + tid], cs[tid]);
    }
}

// ---------------------------------------------------------------------------
// Kernel 3: loss (proven, unchanged).
__global__ void loss_kernel(const float* __restrict__ pos,
                            const float* __restrict__ denom,
                            float* __restrict__ out) {
    int r = blockIdx.x * 256 + threadIdx.x;   // 0..8191
    float s = __logf(denom[r]) - 2.0f * pos[r & (N_ROWS - 1)];
    for (int o = 32; o; o >>= 1) s += __shfl_down(s, o);
    __shared__ float red[4];
    int t = threadIdx.x;
    if ((t & 63) == 0) red[t >> 6] = s;
    __syncthreads();
    if (t == 0)
        atomicAdd(out, (red[0] + red[1] + red[2] + red[3]) / (float)TWO_N);
}

// ---------------------------------------------------------------------------
extern "C" void kernel_launch(void* const* d_in, const int* in_sizes, int n_in,
                              void* d_out, int out_size, void* d_ws, size_t ws_size,
                              hipStream_t stream) {
    const float* ei = (const float*)d_in[0];
    const float* ej = (const float*)d_in[1];

    // ws layout: zq (fp8, 2N*D = 4 MB) | pos (N f32) | denom (2N f32)
    unsigned char* zq = (unsigned char*)d_ws;
    float* pos   = (float*)((char*)d_ws + (size_t)TWO_N * DIM);
    float* denom = pos + N_ROWS;
    float* out   = (float*)d_out;

    normalize_kernel<<<N_ROWS, 256, 0, stream>>>(ei, ej, zq, pos, denom, out);
    gemm_exp_kernel<<<NTRI, 256, 0, stream>>>(zq, denom);
    loss_kernel<<<TWO_N / 256, 256, 0, stream>>>(pos, denom, out);
}

// Round 11
// 103.807 us; speedup vs baseline: 2.0285x; 1.0330x over previous
//
#include <hip/hip_runtime.h>
#include <hip/hip_bf16.h>

#define N_ROWS 4096
#define DIM 512                  // elements AND bytes per fp8 row
#define TWO_N 8192
#define NTILE 64                 // 8192 / 128
#define NTRI  (NTILE * (NTILE + 1) / 2)   // 2080 upper-tri 128x128 blocks

typedef float f32x4 __attribute__((ext_vector_type(4)));
typedef long long ll2 __attribute__((ext_vector_type(2)));

// ---------------------------------------------------------------------------
// async global -> LDS, 16 bytes per lane (wave-uniform LDS base + lane*16)
__device__ inline void g2l16(const void* g, void* l) {
    __builtin_amdgcn_global_load_lds(
        (const __attribute__((address_space(1))) void*)g,
        (__attribute__((address_space(3))) void*)l,
        16, 0, 0);
}

// ---------------------------------------------------------------------------
// Kernel 1: normalize rows; emit fp8-e4m3 z rows in SLOT-PERMUTED order:
// within each 128-B K-tile, phys 16-B granule p holds logical 8-B slots
// A = 8*(p>>2)+(p&3) (low half) and A+4 (high half). This lets the gemm
// fetch a lane's kk=2c AND kk=2c+1 fragments with ONE ds_read_b128 at the
// PMC-proven conflict-free granule pattern ((c*4+quad)^(m&7)).
// pos[] stays full f32 (exact positives).
__global__ void normalize_kernel(const float* __restrict__ ei,
                                 const float* __restrict__ ej,
                                 unsigned char* __restrict__ zq,
                                 float* __restrict__ pos,
                                 float* __restrict__ denom,
                                 float* __restrict__ out) {
    int r = blockIdx.x;          // 0..4095
    int t = threadIdx.x;         // 0..255, 2 dims each
    const float2 vi = ((const float2*)(ei + (size_t)r * DIM))[t];
    const float2 vj = ((const float2*)(ej + (size_t)r * DIM))[t];
    float si  = vi.x * vi.x + vi.y * vi.y;
    float sj  = vj.x * vj.x + vj.y * vj.y;
    float sij = vi.x * vj.x + vi.y * vj.y;

    for (int o = 32; o; o >>= 1) {
        si  += __shfl_down(si, o);
        sj  += __shfl_down(sj, o);
        sij += __shfl_down(sij, o);
    }
    __shared__ float red[3][4];
    int wave = t >> 6, lane = t & 63;
    if (lane == 0) { red[0][wave] = si; red[1][wave] = sj; red[2][wave] = sij; }
    __syncthreads();
    si  = red[0][0] + red[0][1] + red[0][2] + red[0][3];
    sj  = red[1][0] + red[1][1] + red[1][2] + red[1][3];
    sij = red[2][0] + red[2][1] + red[2][2] + red[2][3];

    float rni = 1.0f / fmaxf(sqrtf(si), 1e-12f);
    float rnj = 1.0f / fmaxf(sqrtf(sj), 1e-12f);
    if (t == 0) {
        pos[r] = sij * rni * rnj;
        denom[r] = 0.0f;
        denom[r + N_ROWS] = 0.0f;
        if (r == 0) out[0] = 0.0f;
    }
    // pack 2 f32 -> 2 fp8 e4m3 (OCP, RNE); bytes 2t,2t+1 stay adjacent
    // under the slot permutation (slots move whole; 2t,2t+1 share slot).
    int pi8 = __builtin_amdgcn_cvt_pk_fp8_f32(vi.x * rni, vi.y * rni, 0, false);
    int pj8 = __builtin_amdgcn_cvt_pk_fp8_f32(vj.x * rnj, vj.y * rnj, 0, false);

    int kt   = t >> 6;                 // K-tile 0..3 (128 B each)
    int s8   = (t & 63) >> 2;          // logical 8-B slot in tile, 0..15
    int p    = ((s8 >> 3) << 2) | (s8 & 3);   // phys granule 0..7
    int half = (s8 >> 2) & 1;                  // low/high 8 B of granule
    int idx16 = kt * 64 + p * 8 + half * 4 + (t & 3);   // ushort index

    ((unsigned short*)(zq + (size_t)r * DIM))[idx16] = (unsigned short)pi8;
    ((unsigned short*)(zq + (size_t)(r + N_ROWS) * DIM))[idx16] = (unsigned short)pj8;
}

// ---------------------------------------------------------------------------
// Kernel 2 (v11): v10's fp8 structure with the LDS read widened to b128.
// Per K-tile (128 B), per c in {0,1}: ONE ds_read_b128 per fragment at
// phys granule (((c<<2)|quad)^(m&7)) -> low 8 B = kk=2c frag, high 8 B =
// kk=2c+1 frag (thanks to the permuted zq layout). Identical granule
// pattern to the bf16 kernel that measured 0 bank conflicts; LDS read
// instruction count halves (32 -> 16 per tile per lane).
// Staging code identical (linear LDS dest, source granule (l&7)^(l>>3)).
__global__ __launch_bounds__(256, 4) void gemm_exp_kernel(
        const unsigned char* __restrict__ zq,
        float* __restrict__ denom) {
    // ---- XCD-chunked swizzle (proven R9), then linear -> (by, bx) ----
    const int w = blockIdx.x;
    const int t = (w & 7) * (NTRI / 8) + (w >> 3);
    int by = (int)(0.5f * (2.0f * NTILE + 1.0f -
              sqrtf((2.0f * NTILE + 1.0f) * (2.0f * NTILE + 1.0f) - 8.0f * t)));
    while ((by + 1) * NTILE - ((by + 1) * by) / 2 <= t) ++by;
    while (by * NTILE - (by * (by - 1)) / 2 > t) --by;
    const int bx = by + (t - (by * NTILE - (by * (by - 1)) / 2));

    const int rb = by * 128, cb = bx * 128;
    const bool diag = (rb == cb);

    const int tid  = threadIdx.x;
    const int wave = tid >> 6;
    const int lane = tid & 63;
    const int quad = lane >> 4;          // 0..3
    const int m    = lane & 15;          // 0..15
    const int wm   = (wave >> 1) * 64;   // wave row offset in tile
    const int wn   = (wave & 1) * 64;    // wave col offset in tile

    __shared__ __align__(16) unsigned char As[128 * 128];   // 16 KB
    __shared__ __align__(16) unsigned char Bs[128 * 128];   // 16 KB

    f32x4 acc[4][4];
    #pragma unroll
    for (int i = 0; i < 4; ++i)
        #pragma unroll
        for (int j = 0; j < 4; ++j)
            #pragma unroll
            for (int r = 0; r < 4; ++r) acc[i][j][r] = 0.0f;

    // staging: chunk = 1KB = 8 rows x 8 granules(16B); wave w stages chunks
    // 4w..4w+3 of A and B. lane l -> row l>>3, phys granule l&7, source
    // granule (l&7)^(l>>3)  => LDS phys slot s at row r = source s^(r&7).
    const int srow8 = lane >> 3;
    const int sk    = (((lane & 7) ^ srow8) * 16);   // pre-swizzled src bytes

    for (int it = 0; it < 4; ++it) {     // 4 K-tiles of 128 B
        if (it) __syncthreads();         // readers of previous tile done
        const int k0 = it * 128;         // byte offset in row
        #pragma unroll
        for (int cc = 0; cc < 4; ++cc) {
            int c   = 4 * wave + cc;
            int row = c * 8 + srow8;
            g2l16(zq + (size_t)(rb + row) * DIM + k0 + sk, As + c * 1024);
            g2l16(zq + (size_t)(cb + row) * DIM + k0 + sk, Bs + c * 1024);
        }
        __syncthreads();                 // implicit vmcnt drain: tile visible

        #pragma unroll
        for (int c = 0; c < 2; ++c) {    // two kk-pairs (kk=2c, 2c+1)
            const int sl = ((((c << 2) | quad) ^ (m & 7)) * 16);
            ll2 af[4], bfr[4];
            #pragma unroll
            for (int i = 0; i < 4; ++i)
                af[i] = *(const ll2*)(As + (wm + i * 16 + m) * 128 + sl);
            #pragma unroll
            for (int j = 0; j < 4; ++j)
                bfr[j] = *(const ll2*)(Bs + (wn + j * 16 + m) * 128 + sl);

            #pragma unroll
            for (int i = 0; i < 4; ++i)
                #pragma unroll
                for (int j = 0; j < 4; ++j) {
                    acc[i][j] = __builtin_amdgcn_mfma_f32_16x16x32_fp8_fp8(
                        af[i][0], bfr[j][0], acc[i][j], 0, 0, 0);
                    acc[i][j] = __builtin_amdgcn_mfma_f32_16x16x32_fp8_fp8(
                        af[i][1], bfr[j][1], acc[i][j], 0, 0, 0);
                }
        }
    }

    // all waves done with final ds_reads before reusing As as scratch
    __syncthreads();

    // ---- epilogue: exp(2*sim), mask diag, row sums (+ col sums off-diag) ----
    float* rs = (float*)As;            // rowsum[128] | colsum[128]
    float* cs = rs + 128;
    if (tid < 128) { rs[tid] = 0.0f; cs[tid] = 0.0f; }
    __syncthreads();

    float colsum[4] = {0.0f, 0.0f, 0.0f, 0.0f};
    #pragma unroll
    for (int i = 0; i < 4; ++i) {
        #pragma unroll
        for (int r = 0; r < 4; ++r) {
            int lrow = wm + i * 16 + quad * 4 + r;    // local row 0..127
            int grow = rb + lrow;
            float s = 0.0f;
            #pragma unroll
            for (int j = 0; j < 4; ++j) {
                int gcol = cb + wn + j * 16 + m;
                float v  = __expf(2.0f * acc[i][j][r]);
                v = (grow == gcol) ? 0.0f : v;
                s += v;
                colsum[j] += v;
            }
            s += __shfl_xor(s, 1);
            s += __shfl_xor(s, 2);
            s += __shfl_xor(s, 4);
            s += __shfl_xor(s, 8);
            if (m == 0) atomicAdd(&rs[lrow], s);
        }
    }
    if (!diag) {
        #pragma unroll
        for (int j = 0; j < 4; ++j) {
            float s = colsum[j];       // this wave's 64 rows, col wn+j*16+m
            s += __shfl_xor(s, 16);
            s += __shfl_xor(s, 32);
            if (quad == 0) atomicAdd(&cs[wn + j * 16 + m], s);
        }
    }
    __syncthreads();
    if (tid < 128) {
        atomicAdd(&denom[rb + tid], rs[tid]);
        if (!diag) atomicAdd(&denom[cb + tid], cs[tid]);
    }
}

// ---------------------------------------------------------------------------
// Kernel 3: loss (proven, unchanged).
__global__ void loss_kernel(const float* __restrict__ pos,
                            const float* __restrict__ denom,
                            float* __restrict__ out) {
    int r = blockIdx.x * 256 + threadIdx.x;   // 0..8191
    float s = __logf(denom[r]) - 2.0f * pos[r & (N_ROWS - 1)];
    for (int o = 32; o; o >>= 1) s += __shfl_down(s, o);
    __shared__ float red[4];
    int t = threadIdx.x;
    if ((t & 63) == 0) red[t >> 6] = s;
    __syncthreads();
    if (t == 0)
        atomicAdd(out, (red[0] + red[1] + red[2] + red[3]) / (float)TWO_N);
}

// ---------------------------------------------------------------------------
extern "C" void kernel_launch(void* const* d_in, const int* in_sizes, int n_in,
                              void* d_out, int out_size, void* d_ws, size_t ws_size,
                              hipStream_t stream) {
    const float* ei = (const float*)d_in[0];
    const float* ej = (const float*)d_in[1];

    // ws layout: zq (fp8, 2N*D = 4 MB) | pos (N f32) | denom (2N f32)
    unsigned char* zq = (unsigned char*)d_ws;
    float* pos   = (float*)((char*)d_ws + (size_t)TWO_N * DIM);
    float* denom = pos + N_ROWS;
    float* out   = (float*)d_out;

    normalize_kernel<<<N_ROWS, 256, 0, stream>>>(ei, ej, zq, pos, denom, out);
    gemm_exp_kernel<<<NTRI, 256, 0, stream>>>(zq, denom);
    loss_kernel<<<TWO_N / 256, 256, 0, stream>>>(pos, denom, out);
}